// Round 4
// baseline (473.717 us; speedup 1.0000x reference)
//
#include <hip/hip_runtime.h>
#include <stdint.h>

typedef unsigned short u16;
typedef unsigned int u32;

typedef __bf16 bf16x8 __attribute__((ext_vector_type(8)));
typedef float f32x4 __attribute__((ext_vector_type(4)));

#define NQ 6291456   // B*S*AD = 16*512*768
#define NW 589824    // 768*768
#define INV_SCALE 0.03608439182435161f  // 1/sqrt(768)
#define LOG2E2 2.885390081777927f       // 2*log2(e)

__device__ __forceinline__ u16 f2bf(float f) {
    u32 u = __float_as_uint(f);
    u32 r = (u + 0x7fffu + ((u >> 16) & 1u)) >> 16;
    return (u16)r;
}

// p = exp(tanh(s) * INV_SCALE); tanh via 1 exp2 + rcp, outer exp via 3-term
// poly (|arg| <= 0.0361 -> rel err ~7e-8)
__device__ __forceinline__ float score_p(float s) {
    float e  = exp2f(LOG2E2 * s);
    float th = 1.f - __fdividef(2.f, e + 1.f);
    float a  = th * INV_SCALE;
    return fmaf(a, fmaf(a, fmaf(a, 0.16666667f, 0.5f), 1.f), 1.f);
}

__device__ __forceinline__ void gload_lds16(const void* g, void* l) {
    __builtin_amdgcn_global_load_lds(
        (const __attribute__((address_space(1))) char*)(uintptr_t)g,
        (__attribute__((address_space(3))) char*)(uintptr_t)l, 16, 0, 0);
}

__device__ __forceinline__ f32x4 mfma16(bf16x8 a, bf16x8 b, f32x4 c) {
    return __builtin_amdgcn_mfma_f32_16x16x32_bf16(a, b, c, 0, 0, 0);
}

#define LDS_FENCE() asm volatile("s_waitcnt lgkmcnt(0)" ::: "memory")

// ---------------------------------------------------------------------------
// fp32 -> bf16 conversion for all 8 tensors in ONE launch.
// ---------------------------------------------------------------------------
struct CvtArgs {
    const float* src[8];
    u16* dst[8];
    int blk_start[8];
    int n4[8];
};

__global__ __launch_bounds__(256) void cvt_multi(CvtArgs a)
{
    const int bid = blockIdx.x;
    int seg = 0;
#pragma unroll
    for (int s = 1; s < 8; ++s) seg += (bid >= a.blk_start[s]);
    const int i = (bid - a.blk_start[seg]) * 256 + threadIdx.x;
    if (i < a.n4[seg]) {
        float4 v = ((const float4*)a.src[seg])[i];
        ushort4 o;
        o.x = f2bf(v.x); o.y = f2bf(v.y); o.z = f2bf(v.z); o.w = f2bf(v.w);
        ((ushort4*)a.dst[seg])[i] = o;
    }
}

// ---------------------------------------------------------------------------
// Fused q/k/v projection GEMM: C[M,N] = A[M,K] @ W[N,K]^T + bias
// M=8192, N=768, K=768.  grid=(64,6,3): z selects (q|k|v).
// 128x128 tile, BK=64, double-buffered LDS (T3 minimum 2-phase).
// ---------------------------------------------------------------------------
__global__ __launch_bounds__(256, 2) void proj_gemm(
    const u16* __restrict__ A0, const u16* __restrict__ A1,
    const u16* __restrict__ Wq, const u16* __restrict__ Wk, const u16* __restrict__ Wv,
    const float* __restrict__ bq, const float* __restrict__ bk, const float* __restrict__ bv,
    u16* __restrict__ oq, u16* __restrict__ ok, u16* __restrict__ ov)
{
    __shared__ u16 sA[2][8192];
    __shared__ u16 sB[2][8192];

    const int z = blockIdx.z;
    const u16* A       = (z == 0) ? A0 : A1;
    const u16* W       = (z == 0) ? Wq : ((z == 1) ? Wk : Wv);
    const float* bias  = (z == 0) ? bq : ((z == 1) ? bk : bv);
    u16* out           = (z == 0) ? oq : ((z == 1) ? ok : ov);

    const int tid = threadIdx.x;
    const int wave = tid >> 6, lane = tid & 63;
    const int m0 = blockIdx.x * 128, n0 = blockIdx.y * 128;
    const int wrow = wave >> 1, wcol = wave & 1;
    const int lr = lane & 15, lg = lane >> 4;

    const int Lb0 = wave * 4096;
    const int srow = (Lb0 + lane * 16) >> 7;
    const int ssl = (lane & 7);

    f32x4 acc[4][4];
#pragma unroll
    for (int mi = 0; mi < 4; ++mi)
#pragma unroll
        for (int ni = 0; ni < 4; ++ni)
            acc[mi][ni] = (f32x4){0.f, 0.f, 0.f, 0.f};

#define STAGE(buf, k0)                                                          \
    {                                                                           \
        _Pragma("unroll")                                                       \
        for (int i = 0; i < 4; ++i) {                                           \
            const int row = srow + i * 8;                                       \
            const int sc16 = ssl ^ (row & 7);                                   \
            gload_lds16(A + (size_t)(m0 + row) * 768 + (k0) + sc16 * 8,         \
                        (char*)sA[buf] + Lb0 + i * 1024);                       \
            gload_lds16(W + (size_t)(n0 + row) * 768 + (k0) + sc16 * 8,         \
                        (char*)sB[buf] + Lb0 + i * 1024);                       \
        }                                                                       \
    }

    STAGE(0, 0);
    __syncthreads();

    for (int ks = 0; ks < 12; ++ks) {
        const int cur = ks & 1;
        if (ks < 11) STAGE(cur ^ 1, (ks + 1) * 64);
#pragma unroll
        for (int kk = 0; kk < 2; ++kk) {
            bf16x8 af[4], bfr[4];
#pragma unroll
            for (int t = 0; t < 4; ++t) {
                const int ar = wrow * 64 + t * 16 + lr;
                const int ac = (kk * 4 + lg) ^ (ar & 7);
                af[t] = *(const bf16x8*)((const char*)sA[cur] + ar * 128 + ac * 16);
                const int br = wcol * 64 + t * 16 + lr;
                const int bc = (kk * 4 + lg) ^ (br & 7);
                bfr[t] = *(const bf16x8*)((const char*)sB[cur] + br * 128 + bc * 16);
            }
#pragma unroll
            for (int mi = 0; mi < 4; ++mi)
#pragma unroll
                for (int ni = 0; ni < 4; ++ni)
                    acc[mi][ni] = mfma16(af[mi], bfr[ni], acc[mi][ni]);
        }
        __syncthreads();
    }
#undef STAGE

    float bvv[4] = {0.f, 0.f, 0.f, 0.f};
    if (bias) {
#pragma unroll
        for (int ni = 0; ni < 4; ++ni)
            bvv[ni] = bias[n0 + wcol * 64 + ni * 16 + lr];
    }
#pragma unroll
    for (int mi = 0; mi < 4; ++mi) {
#pragma unroll
        for (int ni = 0; ni < 4; ++ni) {
#pragma unroll
            for (int r = 0; r < 4; ++r) {
                const int rowM = m0 + wrow * 64 + mi * 16 + lg * 4 + r;
                const int colN = n0 + wcol * 64 + ni * 16 + lr;
                out[(size_t)rowM * 768 + colN] = f2bf(acc[mi][ni][r] + bvv[ni]);
            }
        }
    }
}

// ---------------------------------------------------------------------------
// V transpose: v[b][s][h*64+d] -> vT[b][h][d][s]
// ---------------------------------------------------------------------------
__global__ __launch_bounds__(256) void vtrans(const u16* __restrict__ v, u16* __restrict__ vT)
{
    __shared__ u16 t[64][80];
    const int blk = blockIdx.x;
    const int b = blk / 96, h = (blk / 8) % 12, st = blk & 7;
    const int tid = threadIdx.x;

    const u16* src = v + (size_t)(b * 512 + st * 64) * 768 + h * 64;
#pragma unroll
    for (int p = 0; p < 2; ++p) {
        const int srow = p * 32 + (tid >> 3), dp = tid & 7;
        uint4 d = *(const uint4*)(src + (size_t)srow * 768 + dp * 8);
        *(uint4*)&t[srow][dp * 8] = d;
    }
    __syncthreads();
    u16* dst = vT + (size_t)((b * 12 + h) * 64) * 512 + st * 64;
#pragma unroll
    for (int p = 0; p < 2; ++p) {
        const int drow = p * 32 + (tid >> 3), sp = tid & 7;
        union { u16 u[8]; uint4 v4; } o;
#pragma unroll
        for (int j = 0; j < 8; ++j) o.u[j] = t[sp * 8 + j][drow];
        *(uint4*)(dst + (size_t)drow * 512 + sp * 8) = o.v4;
    }
}

// ---------------------------------------------------------------------------
// Streaming attention (layers 1,2). blk = qc*192 + bh so the 8 q-chunk
// blocks sharing one (b,h)'s K/V have equal blk%8 -> same XCD -> L2 reuse.
// ---------------------------------------------------------------------------
__global__ __launch_bounds__(256, 4) void attn_stream(
    const u16* __restrict__ q, const u16* __restrict__ k, const u16* __restrict__ vT,
    u16* __restrict__ ctx)
{
    __shared__ u16 sS[4][2][640];   // per wave, 2 bufs: 16 rows x 80B stride

    const int blk = blockIdx.x;
    const int bh = blk % 192, qc = blk / 192;
    const int b = bh / 12, h = bh % 12;
    const int tid = threadIdx.x, wave = tid >> 6, lane = tid & 63;
    const int q0 = qc * 64 + wave * 16;
    const int lr = lane & 15, lg = lane >> 4;

    const u16* qbase = q + (size_t)(b * 512 + q0 + lr) * 768 + h * 64 + lg * 8;
    bf16x8 aq0 = *(const bf16x8*)(qbase);
    bf16x8 aq1 = *(const bf16x8*)(qbase + 32);

    const u16* kbase = k + (size_t)(b * 512 + lr) * 768 + h * 64 + lg * 8;
    const u16* vbase = vT + (size_t)((b * 12 + h) * 64 + lr) * 512 + lg * 8;

    char* const myS0 = (char*)sS[wave][0];
    const int rdoff = lr * 80 + ((lg * 16) ^ ((lr & 3) << 4));

    float psum[4] = {0.f, 0.f, 0.f, 0.f};
    f32x4 o[4];
#pragma unroll
    for (int dt = 0; dt < 4; ++dt) o[dt] = (f32x4){0.f, 0.f, 0.f, 0.f};

    for (int w = 0; w < 16; ++w) {
        char* myS = myS0 + (w & 1) * 1280;
        const u16* kb = kbase + (size_t)w * 32 * 768;
        f32x4 s4a = (f32x4){0.f, 0.f, 0.f, 0.f};
        f32x4 s4b = (f32x4){0.f, 0.f, 0.f, 0.f};
        s4a = mfma16(aq0, *(const bf16x8*)kb, s4a);
        s4a = mfma16(aq1, *(const bf16x8*)(kb + 32), s4a);
        const u16* kb2 = kb + 16 * 768;
        s4b = mfma16(aq0, *(const bf16x8*)kb2, s4b);
        s4b = mfma16(aq1, *(const bf16x8*)(kb2 + 32), s4b);

#pragma unroll
        for (int c = 0; c < 2; ++c) {
#pragma unroll
            for (int r = 0; r < 4; ++r) {
                const float s = c ? s4b[r] : s4a[r];
                const float p = score_p(s);
                psum[r] += p;
                const int row = lg * 4 + r;
                const int byte = row * 80 + (((c * 16 + lr) * 2) ^ ((r & 3) << 4));
                *(u16*)(myS + byte) = f2bf(p);
            }
        }
        LDS_FENCE();
        bf16x8 pa = *(const bf16x8*)(myS + rdoff);
#pragma unroll
        for (int dt = 0; dt < 4; ++dt) {
            bf16x8 vb = *(const bf16x8*)(vbase + (size_t)dt * 16 * 512 + w * 32);
            o[dt] = mfma16(pa, vb, o[dt]);
        }
    }

#pragma unroll
    for (int r = 0; r < 4; ++r) {
        psum[r] += __shfl_xor(psum[r], 1);
        psum[r] += __shfl_xor(psum[r], 2);
        psum[r] += __shfl_xor(psum[r], 4);
        psum[r] += __shfl_xor(psum[r], 8);
    }
    float inv[4];
#pragma unroll
    for (int r = 0; r < 4; ++r) inv[r] = 1.f / psum[r];

#pragma unroll
    for (int dt = 0; dt < 4; ++dt) {
#pragma unroll
        for (int r = 0; r < 4; ++r) {
            const size_t gi = (size_t)(b * 512 + q0 + lg * 4 + r) * 768 + h * 64 + dt * 16 + lr;
            ctx[gi] = f2bf(o[dt][r] * inv[r]);
        }
    }
}

// ---------------------------------------------------------------------------
// Final-layer attention, two-pass streaming (no big LDS):
//  pass 1: QK^T + score_p -> psum only (registers)
//  pass 2: recompute QK^T; write fp32 normalized scores directly; bounce bf16
//          P~ through the small swizzled LDS buffer and accumulate PV.
// ---------------------------------------------------------------------------
__global__ __launch_bounds__(256, 4) void attn_final(
    const u16* __restrict__ q, const u16* __restrict__ k, const u16* __restrict__ vT,
    float* __restrict__ ctxf, float* __restrict__ sc)
{
    __shared__ u16 sS[4][2][640];

    const int blk = blockIdx.x;
    const int bh = blk % 192, qc = blk / 192;
    const int b = bh / 12, h = bh % 12;
    const int tid = threadIdx.x, wave = tid >> 6, lane = tid & 63;
    const int q0 = qc * 64 + wave * 16;
    const int lr = lane & 15, lg = lane >> 4;

    const u16* qbase = q + (size_t)(b * 512 + q0 + lr) * 768 + h * 64 + lg * 8;
    bf16x8 aq0 = *(const bf16x8*)(qbase);
    bf16x8 aq1 = *(const bf16x8*)(qbase + 32);

    const u16* kbase = k + (size_t)(b * 512 + lr) * 768 + h * 64 + lg * 8;
    const u16* vbase = vT + (size_t)((b * 12 + h) * 64 + lr) * 512 + lg * 8;

    char* const myS0 = (char*)sS[wave][0];
    const int rdoff = lr * 80 + ((lg * 16) ^ ((lr & 3) << 4));

    // ---- pass 1: psum only ----
    float psum[4] = {0.f, 0.f, 0.f, 0.f};
    for (int w = 0; w < 16; ++w) {
        const u16* kb = kbase + (size_t)w * 32 * 768;
        f32x4 s4a = (f32x4){0.f, 0.f, 0.f, 0.f};
        f32x4 s4b = (f32x4){0.f, 0.f, 0.f, 0.f};
        s4a = mfma16(aq0, *(const bf16x8*)kb, s4a);
        s4a = mfma16(aq1, *(const bf16x8*)(kb + 32), s4a);
        const u16* kb2 = kb + 16 * 768;
        s4b = mfma16(aq0, *(const bf16x8*)kb2, s4b);
        s4b = mfma16(aq1, *(const bf16x8*)(kb2 + 32), s4b);
#pragma unroll
        for (int r = 0; r < 4; ++r)
            psum[r] += score_p(s4a[r]) + score_p(s4b[r]);
    }
#pragma unroll
    for (int r = 0; r < 4; ++r) {
        psum[r] += __shfl_xor(psum[r], 1);
        psum[r] += __shfl_xor(psum[r], 2);
        psum[r] += __shfl_xor(psum[r], 4);
        psum[r] += __shfl_xor(psum[r], 8);
    }
    float inv[4];
#pragma unroll
    for (int r = 0; r < 4; ++r) inv[r] = 1.f / psum[r];

    // ---- pass 2: scores + PV ----
    f32x4 o[4];
#pragma unroll
    for (int dt = 0; dt < 4; ++dt) o[dt] = (f32x4){0.f, 0.f, 0.f, 0.f};

    float* scb = sc + ((size_t)((h * 16 + b) * 512 + q0)) * 512;

    for (int w = 0; w < 16; ++w) {
        char* myS = myS0 + (w & 1) * 1280;
        const u16* kb = kbase + (size_t)w * 32 * 768;
        f32x4 s4a = (f32x4){0.f, 0.f, 0.f, 0.f};
        f32x4 s4b = (f32x4){0.f, 0.f, 0.f, 0.f};
        s4a = mfma16(aq0, *(const bf16x8*)kb, s4a);
        s4a = mfma16(aq1, *(const bf16x8*)(kb + 32), s4a);
        const u16* kb2 = kb + 16 * 768;
        s4b = mfma16(aq0, *(const bf16x8*)kb2, s4b);
        s4b = mfma16(aq1, *(const bf16x8*)(kb2 + 32), s4b);

#pragma unroll
        for (int c = 0; c < 2; ++c) {
#pragma unroll
            for (int r = 0; r < 4; ++r) {
                const float s = c ? s4b[r] : s4a[r];
                const float p = score_p(s);
                const int row = lg * 4 + r;
                scb[(size_t)row * 512 + w * 32 + c * 16 + lr] = p * inv[r];
                const int byte = row * 80 + (((c * 16 + lr) * 2) ^ ((r & 3) << 4));
                *(u16*)(myS + byte) = f2bf(p);
            }
        }
        LDS_FENCE();
        bf16x8 pa = *(const bf16x8*)(myS + rdoff);
#pragma unroll
        for (int dt = 0; dt < 4; ++dt) {
            bf16x8 vb = *(const bf16x8*)(vbase + (size_t)dt * 16 * 512 + w * 32);
            o[dt] = mfma16(pa, vb, o[dt]);
        }
    }

#pragma unroll
    for (int dt = 0; dt < 4; ++dt) {
#pragma unroll
        for (int r = 0; r < 4; ++r) {
            const float val = o[dt][r] * inv[r];
            const size_t gi = (size_t)(b * 512 + q0 + lg * 4 + r) * 768 + h * 64 + dt * 16 + lr;
            ctxf[gi] = val;
            ctxf[gi + (size_t)NQ] = val;
        }
    }
}

// ---------------------------------------------------------------------------
extern "C" void kernel_launch(void* const* d_in, const int* in_sizes, int n_in,
                              void* d_out, int out_size, void* d_ws, size_t ws_size,
                              hipStream_t stream)
{
    if (n_in < 11) return;
    const float* seq1 = (const float*)d_in[0];
    const float* seq2 = (const float*)d_in[1];
    const float* Wq  = (const float*)d_in[2];
    const float* Wk  = (const float*)d_in[3];
    const float* Wv  = (const float*)d_in[4];
    const float* Wq1 = (const float*)d_in[5];
    const float* bq1 = (const float*)d_in[6];
    const float* Wk1 = (const float*)d_in[7];
    const float* bk1 = (const float*)d_in[8];
    const float* Wv1 = (const float*)d_in[9];
    const float* bv1 = (const float*)d_in[10];

    if (ws_size < ((size_t)7 * NQ + 9 * NW) * 2) return;
    u16* ws   = (u16*)d_ws;
    u16* q    = ws;
    u16* kk   = ws + (size_t)NQ;
    u16* vv   = ws + (size_t)2 * NQ;
    u16* vT   = ws + (size_t)3 * NQ;
    u16* ctx  = ws + (size_t)4 * NQ;
    u16* bs1  = ws + (size_t)5 * NQ;
    u16* bs2  = ws + (size_t)6 * NQ;
    u16* bWq  = ws + (size_t)7 * NQ;
    u16* bWk  = bWq  + (size_t)NW;
    u16* bWv  = bWk  + (size_t)NW;
    u16* bWq1 = bWv  + (size_t)NW;
    u16* bWk1 = bWq1 + (size_t)2 * NW;
    u16* bWv1 = bWk1 + (size_t)2 * NW;

    float* out = (float*)d_out;

    CvtArgs ca;
    const float* srcs[8] = {seq1, seq2, Wq, Wk, Wv, Wq1, Wk1, Wv1};
    u16* dsts[8] = {bs1, bs2, bWq, bWk, bWv, bWq1, bWk1, bWv1};
    const int n4s[8] = {NQ/4, NQ/4, NW/4, NW/4, NW/4, NW/2, NW/2, NW/2};
    int acc_blk = 0;
    for (int s = 0; s < 8; ++s) {
        ca.src[s] = srcs[s]; ca.dst[s] = dsts[s]; ca.n4[s] = n4s[s];
        ca.blk_start[s] = acc_blk;
        acc_blk += (n4s[s] + 255) / 256;
    }
    cvt_multi<<<acc_blk, 256, 0, stream>>>(ca);

    dim3 pgrid(64, 6, 3);

    // layer 1 (no bias)
    proj_gemm<<<pgrid, 256, 0, stream>>>(bs1, bs2, bWq, bWk, bWv,
                                         nullptr, nullptr, nullptr, q, kk, vv);
    vtrans<<<1536, 256, 0, stream>>>(vv, vT);
    attn_stream<<<1536, 256, 0, stream>>>(q, kk, vT, ctx);

    // layer 2
    proj_gemm<<<pgrid, 256, 0, stream>>>(ctx, ctx, bWq1, bWk1, bWv1,
                                         bq1, bk1, bv1, q, kk, vv);
    vtrans<<<1536, 256, 0, stream>>>(vv, vT);
    attn_stream<<<1536, 256, 0, stream>>>(q, kk, vT, ctx);

    // layer 3 (fp32 ctx twice + fp32 normalized scores)
    proj_gemm<<<pgrid, 256, 0, stream>>>(ctx, ctx, bWq1 + (size_t)NW, bWk1 + (size_t)NW,
                                         bWv1 + (size_t)NW,
                                         bq1 + 768, bk1 + 768, bv1 + 768, q, kk, vv);
    vtrans<<<1536, 256, 0, stream>>>(vv, vT);
    attn_final<<<1536, 256, 0, stream>>>(q, kk, vT, out, out + (size_t)2 * NQ);
}

// Round 6
// 472.903 us; speedup vs baseline: 1.0017x; 1.0017x over previous
//
#include <hip/hip_runtime.h>
#include <stdint.h>

typedef unsigned short u16;
typedef unsigned int u32;

typedef __bf16 bf16x8 __attribute__((ext_vector_type(8)));
typedef float f32x4 __attribute__((ext_vector_type(4)));

#define NQ 6291456   // B*S*AD = 16*512*768
#define NW 589824    // 768*768
#define NSC 50331648 // H*B*S*S = 12*16*512*512
#define NR 98304     // H*B*S rows
#define INV_SCALE 0.03608439182435161f  // 1/sqrt(768)
#define LOG2E2 2.885390081777927f       // 2*log2(e)

__device__ __forceinline__ u16 f2bf(float f) {
    u32 u = __float_as_uint(f);
    u32 r = (u + 0x7fffu + ((u >> 16) & 1u)) >> 16;
    return (u16)r;
}

// p = exp(tanh(s) * INV_SCALE); tanh via 1 exp2 + rcp, outer exp via 3-term
// poly (|arg| <= 0.0361 -> rel err ~7e-8)
__device__ __forceinline__ float score_p(float s) {
    float e  = exp2f(LOG2E2 * s);
    float th = 1.f - __fdividef(2.f, e + 1.f);
    float a  = th * INV_SCALE;
    return fmaf(a, fmaf(a, fmaf(a, 0.16666667f, 0.5f), 1.f), 1.f);
}

__device__ __forceinline__ void gload_lds16(const void* g, void* l) {
    __builtin_amdgcn_global_load_lds(
        (const __attribute__((address_space(1))) char*)(uintptr_t)g,
        (__attribute__((address_space(3))) char*)(uintptr_t)l, 16, 0, 0);
}

__device__ __forceinline__ f32x4 mfma16(bf16x8 a, bf16x8 b, f32x4 c) {
    return __builtin_amdgcn_mfma_f32_16x16x32_bf16(a, b, c, 0, 0, 0);
}

#define LDS_FENCE() asm volatile("s_waitcnt lgkmcnt(0)" ::: "memory")

// ---------------------------------------------------------------------------
// fp32 -> bf16 conversion for all 8 tensors in ONE launch.
// ---------------------------------------------------------------------------
struct CvtArgs {
    const float* src[8];
    u16* dst[8];
    int blk_start[8];
    int n4[8];
};

__global__ __launch_bounds__(256) void cvt_multi(CvtArgs a)
{
    const int bid = blockIdx.x;
    int seg = 0;
#pragma unroll
    for (int s = 1; s < 8; ++s) seg += (bid >= a.blk_start[s]);
    const int i = (bid - a.blk_start[seg]) * 256 + threadIdx.x;
    if (i < a.n4[seg]) {
        float4 v = ((const float4*)a.src[seg])[i];
        ushort4 o;
        o.x = f2bf(v.x); o.y = f2bf(v.y); o.z = f2bf(v.z); o.w = f2bf(v.w);
        ((ushort4*)a.dst[seg])[i] = o;
    }
}

// ---------------------------------------------------------------------------
// Fused q/k/v projection GEMM: C[M,N] = A[M,K] @ W[N,K]^T + bias
// M=8192, N=768, K=768.  grid=(64,6,3): z selects (q|k|v).
// 128x128 tile, BK=64, double-buffered LDS (T3 minimum 2-phase).
// ---------------------------------------------------------------------------
__global__ __launch_bounds__(256, 2) void proj_gemm(
    const u16* __restrict__ A0, const u16* __restrict__ A1,
    const u16* __restrict__ Wq, const u16* __restrict__ Wk, const u16* __restrict__ Wv,
    const float* __restrict__ bq, const float* __restrict__ bk, const float* __restrict__ bv,
    u16* __restrict__ oq, u16* __restrict__ ok, u16* __restrict__ ov)
{
    __shared__ u16 sA[2][8192];
    __shared__ u16 sB[2][8192];

    const int z = blockIdx.z;
    const u16* A       = (z == 0) ? A0 : A1;
    const u16* W       = (z == 0) ? Wq : ((z == 1) ? Wk : Wv);
    const float* bias  = (z == 0) ? bq : ((z == 1) ? bk : bv);
    u16* out           = (z == 0) ? oq : ((z == 1) ? ok : ov);

    const int tid = threadIdx.x;
    const int wave = tid >> 6, lane = tid & 63;
    const int m0 = blockIdx.x * 128, n0 = blockIdx.y * 128;
    const int wrow = wave >> 1, wcol = wave & 1;
    const int lr = lane & 15, lg = lane >> 4;

    const int Lb0 = wave * 4096;
    const int srow = (Lb0 + lane * 16) >> 7;
    const int ssl = (lane & 7);

    f32x4 acc[4][4];
#pragma unroll
    for (int mi = 0; mi < 4; ++mi)
#pragma unroll
        for (int ni = 0; ni < 4; ++ni)
            acc[mi][ni] = (f32x4){0.f, 0.f, 0.f, 0.f};

#define STAGE(buf, k0)                                                          \
    {                                                                           \
        _Pragma("unroll")                                                       \
        for (int i = 0; i < 4; ++i) {                                           \
            const int row = srow + i * 8;                                       \
            const int sc16 = ssl ^ (row & 7);                                   \
            gload_lds16(A + (size_t)(m0 + row) * 768 + (k0) + sc16 * 8,         \
                        (char*)sA[buf] + Lb0 + i * 1024);                       \
            gload_lds16(W + (size_t)(n0 + row) * 768 + (k0) + sc16 * 8,         \
                        (char*)sB[buf] + Lb0 + i * 1024);                       \
        }                                                                       \
    }

    STAGE(0, 0);
    __syncthreads();

    for (int ks = 0; ks < 12; ++ks) {
        const int cur = ks & 1;
        if (ks < 11) STAGE(cur ^ 1, (ks + 1) * 64);
#pragma unroll
        for (int kk = 0; kk < 2; ++kk) {
            bf16x8 af[4], bfr[4];
#pragma unroll
            for (int t = 0; t < 4; ++t) {
                const int ar = wrow * 64 + t * 16 + lr;
                const int ac = (kk * 4 + lg) ^ (ar & 7);
                af[t] = *(const bf16x8*)((const char*)sA[cur] + ar * 128 + ac * 16);
                const int br = wcol * 64 + t * 16 + lr;
                const int bc = (kk * 4 + lg) ^ (br & 7);
                bfr[t] = *(const bf16x8*)((const char*)sB[cur] + br * 128 + bc * 16);
            }
#pragma unroll
            for (int mi = 0; mi < 4; ++mi)
#pragma unroll
                for (int ni = 0; ni < 4; ++ni)
                    acc[mi][ni] = mfma16(af[mi], bfr[ni], acc[mi][ni]);
        }
        __syncthreads();
    }
#undef STAGE

    float bvv[4] = {0.f, 0.f, 0.f, 0.f};
    if (bias) {
#pragma unroll
        for (int ni = 0; ni < 4; ++ni)
            bvv[ni] = bias[n0 + wcol * 64 + ni * 16 + lr];
    }
#pragma unroll
    for (int mi = 0; mi < 4; ++mi) {
#pragma unroll
        for (int ni = 0; ni < 4; ++ni) {
#pragma unroll
            for (int r = 0; r < 4; ++r) {
                const int rowM = m0 + wrow * 64 + mi * 16 + lg * 4 + r;
                const int colN = n0 + wcol * 64 + ni * 16 + lr;
                out[(size_t)rowM * 768 + colN] = f2bf(acc[mi][ni][r] + bvv[ni]);
            }
        }
    }
}

// ---------------------------------------------------------------------------
// V transpose: v[b][s][h*64+d] -> vT[b][h][d][s]
// ---------------------------------------------------------------------------
__global__ __launch_bounds__(256) void vtrans(const u16* __restrict__ v, u16* __restrict__ vT)
{
    __shared__ u16 t[64][80];
    const int blk = blockIdx.x;
    const int b = blk / 96, h = (blk / 8) % 12, st = blk & 7;
    const int tid = threadIdx.x;

    const u16* src = v + (size_t)(b * 512 + st * 64) * 768 + h * 64;
#pragma unroll
    for (int p = 0; p < 2; ++p) {
        const int srow = p * 32 + (tid >> 3), dp = tid & 7;
        uint4 d = *(const uint4*)(src + (size_t)srow * 768 + dp * 8);
        *(uint4*)&t[srow][dp * 8] = d;
    }
    __syncthreads();
    u16* dst = vT + (size_t)((b * 12 + h) * 64) * 512 + st * 64;
#pragma unroll
    for (int p = 0; p < 2; ++p) {
        const int drow = p * 32 + (tid >> 3), sp = tid & 7;
        union { u16 u[8]; uint4 v4; } o;
#pragma unroll
        for (int j = 0; j < 8; ++j) o.u[j] = t[sp * 8 + j][drow];
        *(uint4*)(dst + (size_t)drow * 512 + sp * 8) = o.v4;
    }
}

// ---------------------------------------------------------------------------
// Streaming attention (layers 1,2). blk = qc*192 + bh so the 8 q-chunk
// blocks sharing one (b,h)'s K/V have equal blk%8 -> same XCD -> L2 reuse.
// ---------------------------------------------------------------------------
__global__ __launch_bounds__(256, 4) void attn_stream(
    const u16* __restrict__ q, const u16* __restrict__ k, const u16* __restrict__ vT,
    u16* __restrict__ ctx)
{
    __shared__ u16 sS[4][2][640];   // per wave, 2 bufs: 16 rows x 80B stride

    const int blk = blockIdx.x;
    const int bh = blk % 192, qc = blk / 192;
    const int b = bh / 12, h = bh % 12;
    const int tid = threadIdx.x, wave = tid >> 6, lane = tid & 63;
    const int q0 = qc * 64 + wave * 16;
    const int lr = lane & 15, lg = lane >> 4;

    const u16* qbase = q + (size_t)(b * 512 + q0 + lr) * 768 + h * 64 + lg * 8;
    bf16x8 aq0 = *(const bf16x8*)(qbase);
    bf16x8 aq1 = *(const bf16x8*)(qbase + 32);

    const u16* kbase = k + (size_t)(b * 512 + lr) * 768 + h * 64 + lg * 8;
    const u16* vbase = vT + (size_t)((b * 12 + h) * 64 + lr) * 512 + lg * 8;

    char* const myS0 = (char*)sS[wave][0];
    const int rdoff = lr * 80 + ((lg * 16) ^ ((lr & 3) << 4));

    float psum[4] = {0.f, 0.f, 0.f, 0.f};
    f32x4 o[4];
#pragma unroll
    for (int dt = 0; dt < 4; ++dt) o[dt] = (f32x4){0.f, 0.f, 0.f, 0.f};

    for (int w = 0; w < 16; ++w) {
        char* myS = myS0 + (w & 1) * 1280;
        const u16* kb = kbase + (size_t)w * 32 * 768;
        f32x4 s4a = (f32x4){0.f, 0.f, 0.f, 0.f};
        f32x4 s4b = (f32x4){0.f, 0.f, 0.f, 0.f};
        s4a = mfma16(aq0, *(const bf16x8*)kb, s4a);
        s4a = mfma16(aq1, *(const bf16x8*)(kb + 32), s4a);
        const u16* kb2 = kb + 16 * 768;
        s4b = mfma16(aq0, *(const bf16x8*)kb2, s4b);
        s4b = mfma16(aq1, *(const bf16x8*)(kb2 + 32), s4b);

#pragma unroll
        for (int c = 0; c < 2; ++c) {
#pragma unroll
            for (int r = 0; r < 4; ++r) {
                const float s = c ? s4b[r] : s4a[r];
                const float p = score_p(s);
                psum[r] += p;
                const int row = lg * 4 + r;
                const int byte = row * 80 + (((c * 16 + lr) * 2) ^ ((r & 3) << 4));
                *(u16*)(myS + byte) = f2bf(p);
            }
        }
        LDS_FENCE();
        bf16x8 pa = *(const bf16x8*)(myS + rdoff);
#pragma unroll
        for (int dt = 0; dt < 4; ++dt) {
            bf16x8 vb = *(const bf16x8*)(vbase + (size_t)dt * 16 * 512 + w * 32);
            o[dt] = mfma16(pa, vb, o[dt]);
        }
    }

#pragma unroll
    for (int r = 0; r < 4; ++r) {
        psum[r] += __shfl_xor(psum[r], 1);
        psum[r] += __shfl_xor(psum[r], 2);
        psum[r] += __shfl_xor(psum[r], 4);
        psum[r] += __shfl_xor(psum[r], 8);
    }
    float inv[4];
#pragma unroll
    for (int r = 0; r < 4; ++r) inv[r] = 1.f / psum[r];

#pragma unroll
    for (int dt = 0; dt < 4; ++dt) {
#pragma unroll
        for (int r = 0; r < 4; ++r) {
            const size_t gi = (size_t)(b * 512 + q0 + lg * 4 + r) * 768 + h * 64 + dt * 16 + lr;
            ctx[gi] = f2bf(o[dt][r] * inv[r]);
        }
    }
}

// ---------------------------------------------------------------------------
// Final-layer attention, SINGLE pass: same pipeline as attn_stream, plus the
// bounce-read P~ fragment (row-contiguous bf16 x8) is dumped with one 16B
// store per window into pbuf (score-layout), and per-row inv goes to invs.
// fp32 ctx written twice.  Normalization of scores happens in score_norm.
// ---------------------------------------------------------------------------
__global__ __launch_bounds__(256, 4) void attn_final_s(
    const u16* __restrict__ q, const u16* __restrict__ k, const u16* __restrict__ vT,
    float* __restrict__ ctxf, u16* __restrict__ pbuf, float* __restrict__ invs)
{
    __shared__ u16 sS[4][2][640];

    const int blk = blockIdx.x;
    const int bh = blk % 192, qc = blk / 192;
    const int b = bh / 12, h = bh % 12;
    const int tid = threadIdx.x, wave = tid >> 6, lane = tid & 63;
    const int q0 = qc * 64 + wave * 16;
    const int lr = lane & 15, lg = lane >> 4;

    const u16* qbase = q + (size_t)(b * 512 + q0 + lr) * 768 + h * 64 + lg * 8;
    bf16x8 aq0 = *(const bf16x8*)(qbase);
    bf16x8 aq1 = *(const bf16x8*)(qbase + 32);

    const u16* kbase = k + (size_t)(b * 512 + lr) * 768 + h * 64 + lg * 8;
    const u16* vbase = vT + (size_t)((b * 12 + h) * 64 + lr) * 512 + lg * 8;

    char* const myS0 = (char*)sS[wave][0];
    const int rdoff = lr * 80 + ((lg * 16) ^ ((lr & 3) << 4));

    // P~ destination: row (q0+lr) of the score matrix, key chunk lg*8 per w
    u16* prow = pbuf + ((size_t)((h * 16 + b) * 512 + q0 + lr)) * 512 + lg * 8;

    float psum[4] = {0.f, 0.f, 0.f, 0.f};
    f32x4 o[4];
#pragma unroll
    for (int dt = 0; dt < 4; ++dt) o[dt] = (f32x4){0.f, 0.f, 0.f, 0.f};

    for (int w = 0; w < 16; ++w) {
        char* myS = myS0 + (w & 1) * 1280;
        const u16* kb = kbase + (size_t)w * 32 * 768;
        f32x4 s4a = (f32x4){0.f, 0.f, 0.f, 0.f};
        f32x4 s4b = (f32x4){0.f, 0.f, 0.f, 0.f};
        s4a = mfma16(aq0, *(const bf16x8*)kb, s4a);
        s4a = mfma16(aq1, *(const bf16x8*)(kb + 32), s4a);
        const u16* kb2 = kb + 16 * 768;
        s4b = mfma16(aq0, *(const bf16x8*)kb2, s4b);
        s4b = mfma16(aq1, *(const bf16x8*)(kb2 + 32), s4b);

#pragma unroll
        for (int c = 0; c < 2; ++c) {
#pragma unroll
            for (int r = 0; r < 4; ++r) {
                const float s = c ? s4b[r] : s4a[r];
                const float p = score_p(s);
                psum[r] += p;
                const int row = lg * 4 + r;
                const int byte = row * 80 + (((c * 16 + lr) * 2) ^ ((r & 3) << 4));
                *(u16*)(myS + byte) = f2bf(p);
            }
        }
        LDS_FENCE();
        bf16x8 pa = *(const bf16x8*)(myS + rdoff);
        *(bf16x8*)(prow + w * 32) = pa;   // unnormalized bf16 P -> scratch
#pragma unroll
        for (int dt = 0; dt < 4; ++dt) {
            bf16x8 vb = *(const bf16x8*)(vbase + (size_t)dt * 16 * 512 + w * 32);
            o[dt] = mfma16(pa, vb, o[dt]);
        }
    }

#pragma unroll
    for (int r = 0; r < 4; ++r) {
        psum[r] += __shfl_xor(psum[r], 1);
        psum[r] += __shfl_xor(psum[r], 2);
        psum[r] += __shfl_xor(psum[r], 4);
        psum[r] += __shfl_xor(psum[r], 8);
    }
    float inv[4];
#pragma unroll
    for (int r = 0; r < 4; ++r) inv[r] = 1.f / psum[r];

    if (lr == 0) {
        const int ibase = (h * 16 + b) * 512 + q0 + lg * 4;
#pragma unroll
        for (int r = 0; r < 4; ++r) invs[ibase + r] = inv[r];
    }

#pragma unroll
    for (int dt = 0; dt < 4; ++dt) {
#pragma unroll
        for (int r = 0; r < 4; ++r) {
            const float val = o[dt][r] * inv[r];
            const size_t gi = (size_t)(b * 512 + q0 + lg * 4 + r) * 768 + h * 64 + dt * 16 + lr;
            ctxf[gi] = val;
            ctxf[gi + (size_t)NQ] = val;
        }
    }
}

// ---------------------------------------------------------------------------
// Score normalization: sc[row][key] = fp32(pbuf[row][key]) * invs[row].
// Fully coalesced: 16B bf16 in, 2x16B fp32 out per thread.
// ---------------------------------------------------------------------------
__global__ __launch_bounds__(256) void score_norm(
    const u16* __restrict__ pbuf, const float* __restrict__ invs,
    float* __restrict__ sc)
{
    const int i = blockIdx.x * 256 + threadIdx.x;   // 8-key chunk id
    const int row = i >> 6;                          // 64 chunks per 512-key row
    const float inv = invs[row];
    const size_t base = ((size_t)row * 512) + (i & 63) * 8;
    bf16x8 p = *(const bf16x8*)(pbuf + base);
    float4 o0, o1;
    o0.x = (float)p[0] * inv; o0.y = (float)p[1] * inv;
    o0.z = (float)p[2] * inv; o0.w = (float)p[3] * inv;
    o1.x = (float)p[4] * inv; o1.y = (float)p[5] * inv;
    o1.z = (float)p[6] * inv; o1.w = (float)p[7] * inv;
    float* dst = sc + base;
    *(float4*)dst = o0;
    *(float4*)(dst + 4) = o1;
}

// ---------------------------------------------------------------------------
extern "C" void kernel_launch(void* const* d_in, const int* in_sizes, int n_in,
                              void* d_out, int out_size, void* d_ws, size_t ws_size,
                              hipStream_t stream)
{
    if (n_in < 11) return;
    const float* seq1 = (const float*)d_in[0];
    const float* seq2 = (const float*)d_in[1];
    const float* Wq  = (const float*)d_in[2];
    const float* Wk  = (const float*)d_in[3];
    const float* Wv  = (const float*)d_in[4];
    const float* Wq1 = (const float*)d_in[5];
    const float* bq1 = (const float*)d_in[6];
    const float* Wk1 = (const float*)d_in[7];
    const float* bk1 = (const float*)d_in[8];
    const float* Wv1 = (const float*)d_in[9];
    const float* bv1 = (const float*)d_in[10];

    const size_t need = ((size_t)7 * NQ + 9 * NW + NSC) * 2 + (size_t)NR * 4;
    if (ws_size < need) return;
    u16* ws   = (u16*)d_ws;
    u16* q    = ws;
    u16* kk   = ws + (size_t)NQ;
    u16* vv   = ws + (size_t)2 * NQ;
    u16* vT   = ws + (size_t)3 * NQ;
    u16* ctx  = ws + (size_t)4 * NQ;
    u16* bs1  = ws + (size_t)5 * NQ;
    u16* bs2  = ws + (size_t)6 * NQ;
    u16* bWq  = ws + (size_t)7 * NQ;
    u16* bWk  = bWq  + (size_t)NW;
    u16* bWv  = bWk  + (size_t)NW;
    u16* bWq1 = bWv  + (size_t)NW;
    u16* bWk1 = bWq1 + (size_t)2 * NW;
    u16* bWv1 = bWk1 + (size_t)2 * NW;
    u16* pbuf = bWv1 + (size_t)2 * NW;
    float* invs = (float*)(pbuf + (size_t)NSC);

    float* out = (float*)d_out;

    CvtArgs ca;
    const float* srcs[8] = {seq1, seq2, Wq, Wk, Wv, Wq1, Wk1, Wv1};
    u16* dsts[8] = {bs1, bs2, bWq, bWk, bWv, bWq1, bWk1, bWv1};
    const int n4s[8] = {NQ/4, NQ/4, NW/4, NW/4, NW/4, NW/2, NW/2, NW/2};
    int acc_blk = 0;
    for (int s = 0; s < 8; ++s) {
        ca.src[s] = srcs[s]; ca.dst[s] = dsts[s]; ca.n4[s] = n4s[s];
        ca.blk_start[s] = acc_blk;
        acc_blk += (n4s[s] + 255) / 256;
    }
    cvt_multi<<<acc_blk, 256, 0, stream>>>(ca);

    dim3 pgrid(64, 6, 3);

    // layer 1 (no bias)
    proj_gemm<<<pgrid, 256, 0, stream>>>(bs1, bs2, bWq, bWk, bWv,
                                         nullptr, nullptr, nullptr, q, kk, vv);
    vtrans<<<1536, 256, 0, stream>>>(vv, vT);
    attn_stream<<<1536, 256, 0, stream>>>(q, kk, vT, ctx);

    // layer 2
    proj_gemm<<<pgrid, 256, 0, stream>>>(ctx, ctx, bWq1, bWk1, bWv1,
                                         bq1, bk1, bv1, q, kk, vv);
    vtrans<<<1536, 256, 0, stream>>>(vv, vT);
    attn_stream<<<1536, 256, 0, stream>>>(q, kk, vT, ctx);

    // layer 3: single-pass attn -> fp32 ctx x2 + bf16 P~ + inv, then normalize
    proj_gemm<<<pgrid, 256, 0, stream>>>(ctx, ctx, bWq1 + (size_t)NW, bWk1 + (size_t)NW,
                                         bWv1 + (size_t)NW,
                                         bq1 + 768, bk1 + 768, bv1 + 768, q, kk, vv);
    vtrans<<<1536, 256, 0, stream>>>(vv, vT);
    attn_final_s<<<1536, 256, 0, stream>>>(q, kk, vT, out, pbuf, invs);
    score_norm<<<NSC / 8 / 256, 256, 0, stream>>>(pbuf, invs, out + (size_t)2 * NQ);
}

// Round 7
// 465.748 us; speedup vs baseline: 1.0171x; 1.0154x over previous
//
#include <hip/hip_runtime.h>
#include <stdint.h>

typedef unsigned short u16;
typedef unsigned int u32;

typedef __bf16 bf16x8 __attribute__((ext_vector_type(8)));
typedef float f32x4 __attribute__((ext_vector_type(4)));
typedef float f32x16 __attribute__((ext_vector_type(16)));

#define NQ 6291456   // B*S*AD = 16*512*768
#define NW 589824    // 768*768
#define INV_SCALE 0.03608439182435161f  // 1/sqrt(768)
#define LOG2E2 2.885390081777927f       // 2*log2(e)

__device__ __forceinline__ u16 f2bf(float f) {
    u32 u = __float_as_uint(f);
    u32 r = (u + 0x7fffu + ((u >> 16) & 1u)) >> 16;
    return (u16)r;
}

// p = exp(tanh(s) * INV_SCALE); tanh via 1 exp2 + rcp, outer exp via 3-term
// poly (|arg| <= 0.0361 -> rel err ~7e-8)
__device__ __forceinline__ float score_p(float s) {
    float e  = exp2f(LOG2E2 * s);
    float th = 1.f - __fdividef(2.f, e + 1.f);
    float a  = th * INV_SCALE;
    return fmaf(a, fmaf(a, fmaf(a, 0.16666667f, 0.5f), 1.f), 1.f);
}

__device__ __forceinline__ void gload_lds16(const void* g, void* l) {
    __builtin_amdgcn_global_load_lds(
        (const __attribute__((address_space(1))) char*)(uintptr_t)g,
        (__attribute__((address_space(3))) char*)(uintptr_t)l, 16, 0, 0);
}

__device__ __forceinline__ f32x4 mfma16(bf16x8 a, bf16x8 b, f32x4 c) {
    return __builtin_amdgcn_mfma_f32_16x16x32_bf16(a, b, c, 0, 0, 0);
}
__device__ __forceinline__ f32x16 mfma32(bf16x8 a, bf16x8 b, f32x16 c) {
    return __builtin_amdgcn_mfma_f32_32x32x16_bf16(a, b, c, 0, 0, 0);
}

#define LDS_FENCE() asm volatile("s_waitcnt lgkmcnt(0)" ::: "memory")

// ---------------------------------------------------------------------------
// fp32 -> bf16 conversion for all 8 tensors in ONE launch.
// ---------------------------------------------------------------------------
struct CvtArgs {
    const float* src[8];
    u16* dst[8];
    int blk_start[8];
    int n4[8];
};

__global__ __launch_bounds__(256) void cvt_multi(CvtArgs a)
{
    const int bid = blockIdx.x;
    int seg = 0;
#pragma unroll
    for (int s = 1; s < 8; ++s) seg += (bid >= a.blk_start[s]);
    const int i = (bid - a.blk_start[seg]) * 256 + threadIdx.x;
    if (i < a.n4[seg]) {
        float4 v = ((const float4*)a.src[seg])[i];
        ushort4 o;
        o.x = f2bf(v.x); o.y = f2bf(v.y); o.z = f2bf(v.z); o.w = f2bf(v.w);
        ((ushort4*)a.dst[seg])[i] = o;
    }
}

// ---------------------------------------------------------------------------
// Fused q/k/v projection GEMM: C[M,N] = A[M,K] @ W[N,K]^T + bias
// M=8192, N=768, K=768.  grid=(64,6,3): z selects (q|k|v).
// 128x128 tile, BK=64, double-buffered LDS, 32x32x16 MFMA (2x2 frags/wave).
// C/D layout: col=lane&31, row=(reg&3)+8*(reg>>2)+4*(lane>>5)  [m74/m101]
// ---------------------------------------------------------------------------
__global__ __launch_bounds__(256, 2) void proj_gemm(
    const u16* __restrict__ A0, const u16* __restrict__ A1,
    const u16* __restrict__ Wq, const u16* __restrict__ Wk, const u16* __restrict__ Wv,
    const float* __restrict__ bq, const float* __restrict__ bk, const float* __restrict__ bv,
    u16* __restrict__ oq, u16* __restrict__ ok, u16* __restrict__ ov)
{
    __shared__ u16 sA[2][8192];
    __shared__ u16 sB[2][8192];

    const int z = blockIdx.z;
    const u16* A       = (z == 0) ? A0 : A1;
    const u16* W       = (z == 0) ? Wq : ((z == 1) ? Wk : Wv);
    const float* bias  = (z == 0) ? bq : ((z == 1) ? bk : bv);
    u16* out           = (z == 0) ? oq : ((z == 1) ? ok : ov);

    const int tid = threadIdx.x;
    const int wave = tid >> 6, lane = tid & 63;
    const int m0 = blockIdx.x * 128, n0 = blockIdx.y * 128;
    const int wrow = wave >> 1, wcol = wave & 1;
    const int l31 = lane & 31, l5 = lane >> 5;

    const int Lb0 = wave * 4096;
    const int srow = (Lb0 + lane * 16) >> 7;
    const int ssl = (lane & 7);

    f32x16 acc[2][2];
#pragma unroll
    for (int mi = 0; mi < 2; ++mi)
#pragma unroll
        for (int ni = 0; ni < 2; ++ni)
#pragma unroll
            for (int e = 0; e < 16; ++e)
                acc[mi][ni][e] = 0.f;

#define STAGE(buf, k0)                                                          \
    {                                                                           \
        _Pragma("unroll")                                                       \
        for (int i = 0; i < 4; ++i) {                                           \
            const int row = srow + i * 8;                                       \
            const int sc16 = ssl ^ (row & 7);                                   \
            gload_lds16(A + (size_t)(m0 + row) * 768 + (k0) + sc16 * 8,         \
                        (char*)sA[buf] + Lb0 + i * 1024);                       \
            gload_lds16(W + (size_t)(n0 + row) * 768 + (k0) + sc16 * 8,         \
                        (char*)sB[buf] + Lb0 + i * 1024);                       \
        }                                                                       \
    }

    STAGE(0, 0);
    __syncthreads();

    for (int ks = 0; ks < 12; ++ks) {
        const int cur = ks & 1;
        if (ks < 11) STAGE(cur ^ 1, (ks + 1) * 64);
#pragma unroll
        for (int ks4 = 0; ks4 < 4; ++ks4) {     // 4 x K=16 sub-steps of BK=64
            bf16x8 af[2], bfr[2];
#pragma unroll
            for (int t = 0; t < 2; ++t) {
                const int ar = wrow * 64 + t * 32 + l31;
                const int sa = (ks4 * 2 + l5) ^ (ar & 7);
                af[t] = *(const bf16x8*)((const char*)sA[cur] + ar * 128 + sa * 16);
                const int br = wcol * 64 + t * 32 + l31;
                const int sb = (ks4 * 2 + l5) ^ (br & 7);
                bfr[t] = *(const bf16x8*)((const char*)sB[cur] + br * 128 + sb * 16);
            }
#pragma unroll
            for (int mi = 0; mi < 2; ++mi)
#pragma unroll
                for (int ni = 0; ni < 2; ++ni)
                    acc[mi][ni] = mfma32(af[mi], bfr[ni], acc[mi][ni]);
        }
        __syncthreads();
    }
#undef STAGE

    float bvv[2] = {0.f, 0.f};
    if (bias) {
        bvv[0] = bias[n0 + wcol * 64 + l31];
        bvv[1] = bias[n0 + wcol * 64 + 32 + l31];
    }
#pragma unroll
    for (int mi = 0; mi < 2; ++mi) {
#pragma unroll
        for (int ni = 0; ni < 2; ++ni) {
#pragma unroll
            for (int reg = 0; reg < 16; ++reg) {
                const int rowM = m0 + wrow * 64 + mi * 32 + (reg & 3) + 8 * (reg >> 2) + 4 * l5;
                const int colN = n0 + wcol * 64 + ni * 32 + l31;
                out[(size_t)rowM * 768 + colN] = f2bf(acc[mi][ni][reg] + bvv[ni]);
            }
        }
    }
}

// ---------------------------------------------------------------------------
// V transpose: v[b][s][h*64+d] -> vT[b][h][d][s]
// ---------------------------------------------------------------------------
__global__ __launch_bounds__(256) void vtrans(const u16* __restrict__ v, u16* __restrict__ vT)
{
    __shared__ u16 t[64][80];
    const int blk = blockIdx.x;
    const int b = blk / 96, h = (blk / 8) % 12, st = blk & 7;
    const int tid = threadIdx.x;

    const u16* src = v + (size_t)(b * 512 + st * 64) * 768 + h * 64;
#pragma unroll
    for (int p = 0; p < 2; ++p) {
        const int srow = p * 32 + (tid >> 3), dp = tid & 7;
        uint4 d = *(const uint4*)(src + (size_t)srow * 768 + dp * 8);
        *(uint4*)&t[srow][dp * 8] = d;
    }
    __syncthreads();
    u16* dst = vT + (size_t)((b * 12 + h) * 64) * 512 + st * 64;
#pragma unroll
    for (int p = 0; p < 2; ++p) {
        const int drow = p * 32 + (tid >> 3), sp = tid & 7;
        union { u16 u[8]; uint4 v4; } o;
#pragma unroll
        for (int j = 0; j < 8; ++j) o.u[j] = t[sp * 8 + j][drow];
        *(uint4*)(dst + (size_t)drow * 512 + sp * 8) = o.v4;
    }
}

// ---------------------------------------------------------------------------
// Streaming attention (layers 1,2). blk = qc*192 + bh so the 8 q-chunk
// blocks sharing one (b,h)'s K/V have equal blk%8 -> same XCD -> L2 reuse.
// ---------------------------------------------------------------------------
__global__ __launch_bounds__(256, 4) void attn_stream(
    const u16* __restrict__ q, const u16* __restrict__ k, const u16* __restrict__ vT,
    u16* __restrict__ ctx)
{
    __shared__ u16 sS[4][2][640];   // per wave, 2 bufs: 16 rows x 80B stride

    const int blk = blockIdx.x;
    const int bh = blk % 192, qc = blk / 192;
    const int b = bh / 12, h = bh % 12;
    const int tid = threadIdx.x, wave = tid >> 6, lane = tid & 63;
    const int q0 = qc * 64 + wave * 16;
    const int lr = lane & 15, lg = lane >> 4;

    const u16* qbase = q + (size_t)(b * 512 + q0 + lr) * 768 + h * 64 + lg * 8;
    bf16x8 aq0 = *(const bf16x8*)(qbase);
    bf16x8 aq1 = *(const bf16x8*)(qbase + 32);

    const u16* kbase = k + (size_t)(b * 512 + lr) * 768 + h * 64 + lg * 8;
    const u16* vbase = vT + (size_t)((b * 12 + h) * 64 + lr) * 512 + lg * 8;

    char* const myS0 = (char*)sS[wave][0];
    const int rdoff = lr * 80 + ((lg * 16) ^ ((lr & 3) << 4));

    float psum[4] = {0.f, 0.f, 0.f, 0.f};
    f32x4 o[4];
#pragma unroll
    for (int dt = 0; dt < 4; ++dt) o[dt] = (f32x4){0.f, 0.f, 0.f, 0.f};

    for (int w = 0; w < 16; ++w) {
        char* myS = myS0 + (w & 1) * 1280;
        const u16* kb = kbase + (size_t)w * 32 * 768;
        f32x4 s4a = (f32x4){0.f, 0.f, 0.f, 0.f};
        f32x4 s4b = (f32x4){0.f, 0.f, 0.f, 0.f};
        s4a = mfma16(aq0, *(const bf16x8*)kb, s4a);
        s4a = mfma16(aq1, *(const bf16x8*)(kb + 32), s4a);
        const u16* kb2 = kb + 16 * 768;
        s4b = mfma16(aq0, *(const bf16x8*)kb2, s4b);
        s4b = mfma16(aq1, *(const bf16x8*)(kb2 + 32), s4b);

#pragma unroll
        for (int c = 0; c < 2; ++c) {
#pragma unroll
            for (int r = 0; r < 4; ++r) {
                const float s = c ? s4b[r] : s4a[r];
                const float p = score_p(s);
                psum[r] += p;
                const int row = lg * 4 + r;
                const int byte = row * 80 + (((c * 16 + lr) * 2) ^ ((r & 3) << 4));
                *(u16*)(myS + byte) = f2bf(p);
            }
        }
        LDS_FENCE();
        bf16x8 pa = *(const bf16x8*)(myS + rdoff);
#pragma unroll
        for (int dt = 0; dt < 4; ++dt) {
            bf16x8 vb = *(const bf16x8*)(vbase + (size_t)dt * 16 * 512 + w * 32);
            o[dt] = mfma16(pa, vb, o[dt]);
        }
    }

#pragma unroll
    for (int r = 0; r < 4; ++r) {
        psum[r] += __shfl_xor(psum[r], 1);
        psum[r] += __shfl_xor(psum[r], 2);
        psum[r] += __shfl_xor(psum[r], 4);
        psum[r] += __shfl_xor(psum[r], 8);
    }
    float inv[4];
#pragma unroll
    for (int r = 0; r < 4; ++r) inv[r] = 1.f / psum[r];

#pragma unroll
    for (int dt = 0; dt < 4; ++dt) {
#pragma unroll
        for (int r = 0; r < 4; ++r) {
            const size_t gi = (size_t)(b * 512 + q0 + lg * 4 + r) * 768 + h * 64 + dt * 16 + lr;
            ctx[gi] = f2bf(o[dt][r] * inv[r]);
        }
    }
}

// ---------------------------------------------------------------------------
// Final-layer attention, single pass, NO scratch round-trip: the bounce-read
// P~ fragment (8 keys of row lr) is kept in registers (16 windows = 64 VGPR);
// after psum reduction, inv for row lr is fetched via 4 shuffles and the
// normalized fp32 scores are written directly (2 float4 per window per lane).
// fp32 ctx written twice.
// ---------------------------------------------------------------------------
__global__ __launch_bounds__(256, 4) void attn_final_s(
    const u16* __restrict__ q, const u16* __restrict__ k, const u16* __restrict__ vT,
    float* __restrict__ ctxf, float* __restrict__ sc)
{
    __shared__ u16 sS[4][2][640];

    const int blk = blockIdx.x;
    const int bh = blk % 192, qc = blk / 192;
    const int b = bh / 12, h = bh % 12;
    const int tid = threadIdx.x, wave = tid >> 6, lane = tid & 63;
    const int q0 = qc * 64 + wave * 16;
    const int lr = lane & 15, lg = lane >> 4;

    const u16* qbase = q + (size_t)(b * 512 + q0 + lr) * 768 + h * 64 + lg * 8;
    bf16x8 aq0 = *(const bf16x8*)(qbase);
    bf16x8 aq1 = *(const bf16x8*)(qbase + 32);

    const u16* kbase = k + (size_t)(b * 512 + lr) * 768 + h * 64 + lg * 8;
    const u16* vbase = vT + (size_t)((b * 12 + h) * 64 + lr) * 512 + lg * 8;

    char* const myS0 = (char*)sS[wave][0];
    const int rdoff = lr * 80 + ((lg * 16) ^ ((lr & 3) << 4));

    float psum[4] = {0.f, 0.f, 0.f, 0.f};
    f32x4 o[4];
#pragma unroll
    for (int dt = 0; dt < 4; ++dt) o[dt] = (f32x4){0.f, 0.f, 0.f, 0.f};
    bf16x8 pfrag[16];

#pragma unroll
    for (int w = 0; w < 16; ++w) {
        char* myS = myS0 + (w & 1) * 1280;
        const u16* kb = kbase + (size_t)w * 32 * 768;
        f32x4 s4a = (f32x4){0.f, 0.f, 0.f, 0.f};
        f32x4 s4b = (f32x4){0.f, 0.f, 0.f, 0.f};
        s4a = mfma16(aq0, *(const bf16x8*)kb, s4a);
        s4a = mfma16(aq1, *(const bf16x8*)(kb + 32), s4a);
        const u16* kb2 = kb + 16 * 768;
        s4b = mfma16(aq0, *(const bf16x8*)kb2, s4b);
        s4b = mfma16(aq1, *(const bf16x8*)(kb2 + 32), s4b);

#pragma unroll
        for (int c = 0; c < 2; ++c) {
#pragma unroll
            for (int r = 0; r < 4; ++r) {
                const float s = c ? s4b[r] : s4a[r];
                const float p = score_p(s);
                psum[r] += p;
                const int row = lg * 4 + r;
                const int byte = row * 80 + (((c * 16 + lr) * 2) ^ ((r & 3) << 4));
                *(u16*)(myS + byte) = f2bf(p);
            }
        }
        LDS_FENCE();
        bf16x8 pa = *(const bf16x8*)(myS + rdoff);
        pfrag[w] = pa;
#pragma unroll
        for (int dt = 0; dt < 4; ++dt) {
            bf16x8 vb = *(const bf16x8*)(vbase + (size_t)dt * 16 * 512 + w * 32);
            o[dt] = mfma16(pa, vb, o[dt]);
        }
    }

#pragma unroll
    for (int r = 0; r < 4; ++r) {
        psum[r] += __shfl_xor(psum[r], 1);
        psum[r] += __shfl_xor(psum[r], 2);
        psum[r] += __shfl_xor(psum[r], 4);
        psum[r] += __shfl_xor(psum[r], 8);
    }
    float inv[4];
#pragma unroll
    for (int r = 0; r < 4; ++r) inv[r] = 1.f / psum[r];

    // inv for THIS lane's row lr: held as inv[lr&3] on lanes of group lg=lr>>2
    const int srcl = (lr >> 2) << 4;
    const float v0 = __shfl(inv[0], srcl);
    const float v1 = __shfl(inv[1], srcl);
    const float v2 = __shfl(inv[2], srcl);
    const float v3 = __shfl(inv[3], srcl);
    const int sel = lr & 3;
    const float invlr = (sel == 0) ? v0 : (sel == 1) ? v1 : (sel == 2) ? v2 : v3;

    // normalized fp32 scores, direct write: row q0+lr, cols w*32 + lg*8 ..
    float* scrow = sc + ((size_t)((h * 16 + b) * 512 + q0 + lr)) * 512 + lg * 8;
#pragma unroll
    for (int w = 0; w < 16; ++w) {
        const bf16x8 pf = pfrag[w];
        float4 o0, o1;
        o0.x = (float)pf[0] * invlr; o0.y = (float)pf[1] * invlr;
        o0.z = (float)pf[2] * invlr; o0.w = (float)pf[3] * invlr;
        o1.x = (float)pf[4] * invlr; o1.y = (float)pf[5] * invlr;
        o1.z = (float)pf[6] * invlr; o1.w = (float)pf[7] * invlr;
        *(float4*)(scrow + w * 32) = o0;
        *(float4*)(scrow + w * 32 + 4) = o1;
    }

#pragma unroll
    for (int dt = 0; dt < 4; ++dt) {
#pragma unroll
        for (int r = 0; r < 4; ++r) {
            const float val = o[dt][r] * inv[r];
            const size_t gi = (size_t)(b * 512 + q0 + lg * 4 + r) * 768 + h * 64 + dt * 16 + lr;
            ctxf[gi] = val;
            ctxf[gi + (size_t)NQ] = val;
        }
    }
}

// ---------------------------------------------------------------------------
extern "C" void kernel_launch(void* const* d_in, const int* in_sizes, int n_in,
                              void* d_out, int out_size, void* d_ws, size_t ws_size,
                              hipStream_t stream)
{
    if (n_in < 11) return;
    const float* seq1 = (const float*)d_in[0];
    const float* seq2 = (const float*)d_in[1];
    const float* Wq  = (const float*)d_in[2];
    const float* Wk  = (const float*)d_in[3];
    const float* Wv  = (const float*)d_in[4];
    const float* Wq1 = (const float*)d_in[5];
    const float* bq1 = (const float*)d_in[6];
    const float* Wk1 = (const float*)d_in[7];
    const float* bk1 = (const float*)d_in[8];
    const float* Wv1 = (const float*)d_in[9];
    const float* bv1 = (const float*)d_in[10];

    if (ws_size < ((size_t)7 * NQ + 9 * NW) * 2) return;
    u16* ws   = (u16*)d_ws;
    u16* q    = ws;
    u16* kk   = ws + (size_t)NQ;
    u16* vv   = ws + (size_t)2 * NQ;
    u16* vT   = ws + (size_t)3 * NQ;
    u16* ctx  = ws + (size_t)4 * NQ;
    u16* bs1  = ws + (size_t)5 * NQ;
    u16* bs2  = ws + (size_t)6 * NQ;
    u16* bWq  = ws + (size_t)7 * NQ;
    u16* bWk  = bWq  + (size_t)NW;
    u16* bWv  = bWk  + (size_t)NW;
    u16* bWq1 = bWv  + (size_t)NW;
    u16* bWk1 = bWq1 + (size_t)2 * NW;
    u16* bWv1 = bWk1 + (size_t)2 * NW;

    float* out = (float*)d_out;

    CvtArgs ca;
    const float* srcs[8] = {seq1, seq2, Wq, Wk, Wv, Wq1, Wk1, Wv1};
    u16* dsts[8] = {bs1, bs2, bWq, bWk, bWv, bWq1, bWk1, bWv1};
    const int n4s[8] = {NQ/4, NQ/4, NW/4, NW/4, NW/4, NW/2, NW/2, NW/2};
    int acc_blk = 0;
    for (int s = 0; s < 8; ++s) {
        ca.src[s] = srcs[s]; ca.dst[s] = dsts[s]; ca.n4[s] = n4s[s];
        ca.blk_start[s] = acc_blk;
        acc_blk += (n4s[s] + 255) / 256;
    }
    cvt_multi<<<acc_blk, 256, 0, stream>>>(ca);

    dim3 pgrid(64, 6, 3);

    // layer 1 (no bias)
    proj_gemm<<<pgrid, 256, 0, stream>>>(bs1, bs2, bWq, bWk, bWv,
                                         nullptr, nullptr, nullptr, q, kk, vv);
    vtrans<<<1536, 256, 0, stream>>>(vv, vT);
    attn_stream<<<1536, 256, 0, stream>>>(q, kk, vT, ctx);

    // layer 2
    proj_gemm<<<pgrid, 256, 0, stream>>>(ctx, ctx, bWq1, bWk1, bWv1,
                                         bq1, bk1, bv1, q, kk, vv);
    vtrans<<<1536, 256, 0, stream>>>(vv, vT);
    attn_stream<<<1536, 256, 0, stream>>>(q, kk, vT, ctx);

    // layer 3: fp32 ctx x2 + direct normalized fp32 scores
    proj_gemm<<<pgrid, 256, 0, stream>>>(ctx, ctx, bWq1 + (size_t)NW, bWk1 + (size_t)NW,
                                         bWv1 + (size_t)NW,
                                         bq1 + 768, bk1 + 768, bv1 + 768, q, kk, vv);
    vtrans<<<1536, 256, 0, stream>>>(vv, vT);
    attn_final_s<<<1536, 256, 0, stream>>>(q, kk, vT, out, out + (size_t)2 * NQ);
}

// Round 9
// 460.585 us; speedup vs baseline: 1.0285x; 1.0112x over previous
//
#include <hip/hip_runtime.h>
#include <stdint.h>

typedef unsigned short u16;
typedef unsigned int u32;

typedef __bf16 bf16x8 __attribute__((ext_vector_type(8)));
typedef float f32x4 __attribute__((ext_vector_type(4)));
typedef float f32x16 __attribute__((ext_vector_type(16)));

#define NQ 6291456   // B*S*AD = 16*512*768
#define NW 589824    // 768*768
#define INV_SCALE 0.03608439182435161f  // 1/sqrt(768)
#define LOG2E2 2.885390081777927f       // 2*log2(e)

__device__ __forceinline__ u16 f2bf(float f) {
    u32 u = __float_as_uint(f);
    u32 r = (u + 0x7fffu + ((u >> 16) & 1u)) >> 16;
    return (u16)r;
}

// p = exp(tanh(s) * INV_SCALE); tanh via 1 exp2 + rcp, outer exp via 3-term
// poly (|arg| <= 0.0361 -> rel err ~7e-8)
__device__ __forceinline__ float score_p(float s) {
    float e  = exp2f(LOG2E2 * s);
    float th = 1.f - __fdividef(2.f, e + 1.f);
    float a  = th * INV_SCALE;
    return fmaf(a, fmaf(a, fmaf(a, 0.16666667f, 0.5f), 1.f), 1.f);
}

__device__ __forceinline__ void gload_lds16(const void* g, void* l) {
    __builtin_amdgcn_global_load_lds(
        (const __attribute__((address_space(1))) char*)(uintptr_t)g,
        (__attribute__((address_space(3))) char*)(uintptr_t)l, 16, 0, 0);
}

__device__ __forceinline__ f32x4 mfma16(bf16x8 a, bf16x8 b, f32x4 c) {
    return __builtin_amdgcn_mfma_f32_16x16x32_bf16(a, b, c, 0, 0, 0);
}
__device__ __forceinline__ f32x16 mfma32(bf16x8 a, bf16x8 b, f32x16 c) {
    return __builtin_amdgcn_mfma_f32_32x32x16_bf16(a, b, c, 0, 0, 0);
}

#define LDS_FENCE() asm volatile("s_waitcnt lgkmcnt(0)" ::: "memory")

// ---------------------------------------------------------------------------
// fp32 -> bf16 conversion for all 8 tensors in ONE launch.
// ---------------------------------------------------------------------------
struct CvtArgs {
    const float* src[8];
    u16* dst[8];
    int blk_start[8];
    int n4[8];
};

__global__ __launch_bounds__(256) void cvt_multi(CvtArgs a)
{
    const int bid = blockIdx.x;
    int seg = 0;
#pragma unroll
    for (int s = 1; s < 8; ++s) seg += (bid >= a.blk_start[s]);
    const int i = (bid - a.blk_start[seg]) * 256 + threadIdx.x;
    if (i < a.n4[seg]) {
        float4 v = ((const float4*)a.src[seg])[i];
        ushort4 o;
        o.x = f2bf(v.x); o.y = f2bf(v.y); o.z = f2bf(v.z); o.w = f2bf(v.w);
        ((ushort4*)a.dst[seg])[i] = o;
    }
}

// ---------------------------------------------------------------------------
// Fused q/k/v projection GEMM: C[M,N] = A[M,K] @ W[N,K]^T + bias
// M=8192, N=768, K=768.  grid=(64,6,3): z selects (q|k|v).
// 128x128 tile, BK=64, double-buffered LDS, 32x32x16 MFMA (2x2 frags/wave).
// C/D layout: col=lane&31, row=(reg&3)+8*(reg>>2)+4*(lane>>5)  [m74/m101]
// ---------------------------------------------------------------------------
__global__ __launch_bounds__(256, 2) void proj_gemm(
    const u16* __restrict__ A0, const u16* __restrict__ A1,
    const u16* __restrict__ Wq, const u16* __restrict__ Wk, const u16* __restrict__ Wv,
    const float* __restrict__ bq, const float* __restrict__ bk, const float* __restrict__ bv,
    u16* __restrict__ oq, u16* __restrict__ ok, u16* __restrict__ ov)
{
    __shared__ u16 sA[2][8192];
    __shared__ u16 sB[2][8192];

    const int z = blockIdx.z;
    const u16* A       = (z == 0) ? A0 : A1;
    const u16* W       = (z == 0) ? Wq : ((z == 1) ? Wk : Wv);
    const float* bias  = (z == 0) ? bq : ((z == 1) ? bk : bv);
    u16* out           = (z == 0) ? oq : ((z == 1) ? ok : ov);

    const int tid = threadIdx.x;
    const int wave = tid >> 6, lane = tid & 63;
    const int m0 = blockIdx.x * 128, n0 = blockIdx.y * 128;
    const int wrow = wave >> 1, wcol = wave & 1;
    const int l31 = lane & 31, l5 = lane >> 5;

    const int Lb0 = wave * 4096;
    const int srow = (Lb0 + lane * 16) >> 7;
    const int ssl = (lane & 7);

    f32x16 acc[2][2];
#pragma unroll
    for (int mi = 0; mi < 2; ++mi)
#pragma unroll
        for (int ni = 0; ni < 2; ++ni)
#pragma unroll
            for (int e = 0; e < 16; ++e)
                acc[mi][ni][e] = 0.f;

#define STAGE(buf, k0)                                                          \
    {                                                                           \
        _Pragma("unroll")                                                       \
        for (int i = 0; i < 4; ++i) {                                           \
            const int row = srow + i * 8;                                       \
            const int sc16 = ssl ^ (row & 7);                                   \
            gload_lds16(A + (size_t)(m0 + row) * 768 + (k0) + sc16 * 8,         \
                        (char*)sA[buf] + Lb0 + i * 1024);                       \
            gload_lds16(W + (size_t)(n0 + row) * 768 + (k0) + sc16 * 8,         \
                        (char*)sB[buf] + Lb0 + i * 1024);                       \
        }                                                                       \
    }

    STAGE(0, 0);
    __syncthreads();

    for (int ks = 0; ks < 12; ++ks) {
        const int cur = ks & 1;
        if (ks < 11) STAGE(cur ^ 1, (ks + 1) * 64);
#pragma unroll
        for (int ks4 = 0; ks4 < 4; ++ks4) {     // 4 x K=16 sub-steps of BK=64
            bf16x8 af[2], bfr[2];
#pragma unroll
            for (int t = 0; t < 2; ++t) {
                const int ar = wrow * 64 + t * 32 + l31;
                const int sa = (ks4 * 2 + l5) ^ (ar & 7);
                af[t] = *(const bf16x8*)((const char*)sA[cur] + ar * 128 + sa * 16);
                const int br = wcol * 64 + t * 32 + l31;
                const int sb = (ks4 * 2 + l5) ^ (br & 7);
                bfr[t] = *(const bf16x8*)((const char*)sB[cur] + br * 128 + sb * 16);
            }
#pragma unroll
            for (int mi = 0; mi < 2; ++mi)
#pragma unroll
                for (int ni = 0; ni < 2; ++ni)
                    acc[mi][ni] = mfma32(af[mi], bfr[ni], acc[mi][ni]);
        }
        __syncthreads();
    }
#undef STAGE

    float bvv[2] = {0.f, 0.f};
    if (bias) {
        bvv[0] = bias[n0 + wcol * 64 + l31];
        bvv[1] = bias[n0 + wcol * 64 + 32 + l31];
    }
#pragma unroll
    for (int mi = 0; mi < 2; ++mi) {
#pragma unroll
        for (int ni = 0; ni < 2; ++ni) {
#pragma unroll
            for (int reg = 0; reg < 16; ++reg) {
                const int rowM = m0 + wrow * 64 + mi * 32 + (reg & 3) + 8 * (reg >> 2) + 4 * l5;
                const int colN = n0 + wcol * 64 + ni * 32 + l31;
                out[(size_t)rowM * 768 + colN] = f2bf(acc[mi][ni][reg] + bvv[ni]);
            }
        }
    }
}

// ---------------------------------------------------------------------------
// V transpose: v[b][s][h*64+d] -> vT[b][h][d][s]
// ---------------------------------------------------------------------------
__global__ __launch_bounds__(256) void vtrans(const u16* __restrict__ v, u16* __restrict__ vT)
{
    __shared__ u16 t[64][80];
    const int blk = blockIdx.x;
    const int b = blk / 96, h = (blk / 8) % 12, st = blk & 7;
    const int tid = threadIdx.x;

    const u16* src = v + (size_t)(b * 512 + st * 64) * 768 + h * 64;
#pragma unroll
    for (int p = 0; p < 2; ++p) {
        const int srow = p * 32 + (tid >> 3), dp = tid & 7;
        uint4 d = *(const uint4*)(src + (size_t)srow * 768 + dp * 8);
        *(uint4*)&t[srow][dp * 8] = d;
    }
    __syncthreads();
    u16* dst = vT + (size_t)((b * 12 + h) * 64) * 512 + st * 64;
#pragma unroll
    for (int p = 0; p < 2; ++p) {
        const int drow = p * 32 + (tid >> 3), sp = tid & 7;
        union { u16 u[8]; uint4 v4; } o;
#pragma unroll
        for (int j = 0; j < 8; ++j) o.u[j] = t[sp * 8 + j][drow];
        *(uint4*)(dst + (size_t)drow * 512 + sp * 8) = o.v4;
    }
}

// ---------------------------------------------------------------------------
// Streaming attention (layers 1,2). blk = qc*192 + bh so the 8 q-chunk
// blocks sharing one (b,h)'s K/V have equal blk%8 -> same XCD -> L2 reuse.
// ---------------------------------------------------------------------------
__global__ __launch_bounds__(256, 4) void attn_stream(
    const u16* __restrict__ q, const u16* __restrict__ k, const u16* __restrict__ vT,
    u16* __restrict__ ctx)
{
    __shared__ u16 sS[4][2][640];   // per wave, 2 bufs: 16 rows x 80B stride

    const int blk = blockIdx.x;
    const int bh = blk % 192, qc = blk / 192;
    const int b = bh / 12, h = bh % 12;
    const int tid = threadIdx.x, wave = tid >> 6, lane = tid & 63;
    const int q0 = qc * 64 + wave * 16;
    const int lr = lane & 15, lg = lane >> 4;

    const u16* qbase = q + (size_t)(b * 512 + q0 + lr) * 768 + h * 64 + lg * 8;
    bf16x8 aq0 = *(const bf16x8*)(qbase);
    bf16x8 aq1 = *(const bf16x8*)(qbase + 32);

    const u16* kbase = k + (size_t)(b * 512 + lr) * 768 + h * 64 + lg * 8;
    const u16* vbase = vT + (size_t)((b * 12 + h) * 64 + lr) * 512 + lg * 8;

    char* const myS0 = (char*)sS[wave][0];
    const int rdoff = lr * 80 + ((lg * 16) ^ ((lr & 3) << 4));

    float psum[4] = {0.f, 0.f, 0.f, 0.f};
    f32x4 o[4];
#pragma unroll
    for (int dt = 0; dt < 4; ++dt) o[dt] = (f32x4){0.f, 0.f, 0.f, 0.f};

    for (int w = 0; w < 16; ++w) {
        char* myS = myS0 + (w & 1) * 1280;
        const u16* kb = kbase + (size_t)w * 32 * 768;
        f32x4 s4a = (f32x4){0.f, 0.f, 0.f, 0.f};
        f32x4 s4b = (f32x4){0.f, 0.f, 0.f, 0.f};
        s4a = mfma16(aq0, *(const bf16x8*)kb, s4a);
        s4a = mfma16(aq1, *(const bf16x8*)(kb + 32), s4a);
        const u16* kb2 = kb + 16 * 768;
        s4b = mfma16(aq0, *(const bf16x8*)kb2, s4b);
        s4b = mfma16(aq1, *(const bf16x8*)(kb2 + 32), s4b);

#pragma unroll
        for (int c = 0; c < 2; ++c) {
#pragma unroll
            for (int r = 0; r < 4; ++r) {
                const float s = c ? s4b[r] : s4a[r];
                const float p = score_p(s);
                psum[r] += p;
                const int row = lg * 4 + r;
                const int byte = row * 80 + (((c * 16 + lr) * 2) ^ ((r & 3) << 4));
                *(u16*)(myS + byte) = f2bf(p);
            }
        }
        LDS_FENCE();
        bf16x8 pa = *(const bf16x8*)(myS + rdoff);
#pragma unroll
        for (int dt = 0; dt < 4; ++dt) {
            bf16x8 vb = *(const bf16x8*)(vbase + (size_t)dt * 16 * 512 + w * 32);
            o[dt] = mfma16(pa, vb, o[dt]);
        }
    }

#pragma unroll
    for (int r = 0; r < 4; ++r) {
        psum[r] += __shfl_xor(psum[r], 1);
        psum[r] += __shfl_xor(psum[r], 2);
        psum[r] += __shfl_xor(psum[r], 4);
        psum[r] += __shfl_xor(psum[r], 8);
    }
    float inv[4];
#pragma unroll
    for (int r = 0; r < 4; ++r) inv[r] = 1.f / psum[r];

#pragma unroll
    for (int dt = 0; dt < 4; ++dt) {
#pragma unroll
        for (int r = 0; r < 4; ++r) {
            const size_t gi = (size_t)(b * 512 + q0 + lg * 4 + r) * 768 + h * 64 + dt * 16 + lr;
            ctx[gi] = f2bf(o[dt][r] * inv[r]);
        }
    }
}

// ---------------------------------------------------------------------------
// Final-layer attention, single pass: P~ fragment (8 keys of own row lr) kept
// in registers (16 windows = 64 VGPR).  launch_bounds(256,2): the (256,4)
// variant capped unified VGPR+AGPR at 128 and SPILLED pfrag to scratch
// (round 7: VGPR=60, 200us, all pipes idle).  2 blocks/CU, no spill.
// ---------------------------------------------------------------------------
__global__ __launch_bounds__(256, 2) void attn_final_s(
    const u16* __restrict__ q, const u16* __restrict__ k, const u16* __restrict__ vT,
    float* __restrict__ ctxf, float* __restrict__ sc)
{
    __shared__ u16 sS[4][2][640];

    const int blk = blockIdx.x;
    const int bh = blk % 192, qc = blk / 192;
    const int b = bh / 12, h = bh % 12;
    const int tid = threadIdx.x, wave = tid >> 6, lane = tid & 63;
    const int q0 = qc * 64 + wave * 16;
    const int lr = lane & 15, lg = lane >> 4;

    const u16* qbase = q + (size_t)(b * 512 + q0 + lr) * 768 + h * 64 + lg * 8;
    bf16x8 aq0 = *(const bf16x8*)(qbase);
    bf16x8 aq1 = *(const bf16x8*)(qbase + 32);

    const u16* kbase = k + (size_t)(b * 512 + lr) * 768 + h * 64 + lg * 8;
    const u16* vbase = vT + (size_t)((b * 12 + h) * 64 + lr) * 512 + lg * 8;

    char* const myS0 = (char*)sS[wave][0];
    const int rdoff = lr * 80 + ((lg * 16) ^ ((lr & 3) << 4));

    float psum[4] = {0.f, 0.f, 0.f, 0.f};
    f32x4 o[4];
#pragma unroll
    for (int dt = 0; dt < 4; ++dt) o[dt] = (f32x4){0.f, 0.f, 0.f, 0.f};
    bf16x8 pfrag[16];

#pragma unroll
    for (int w = 0; w < 16; ++w) {
        char* myS = myS0 + (w & 1) * 1280;
        const u16* kb = kbase + (size_t)w * 32 * 768;
        f32x4 s4a = (f32x4){0.f, 0.f, 0.f, 0.f};
        f32x4 s4b = (f32x4){0.f, 0.f, 0.f, 0.f};
        s4a = mfma16(aq0, *(const bf16x8*)kb, s4a);
        s4a = mfma16(aq1, *(const bf16x8*)(kb + 32), s4a);
        const u16* kb2 = kb + 16 * 768;
        s4b = mfma16(aq0, *(const bf16x8*)kb2, s4b);
        s4b = mfma16(aq1, *(const bf16x8*)(kb2 + 32), s4b);

#pragma unroll
        for (int c = 0; c < 2; ++c) {
#pragma unroll
            for (int r = 0; r < 4; ++r) {
                const float s = c ? s4b[r] : s4a[r];
                const float p = score_p(s);
                psum[r] += p;
                const int row = lg * 4 + r;
                const int byte = row * 80 + (((c * 16 + lr) * 2) ^ ((r & 3) << 4));
                *(u16*)(myS + byte) = f2bf(p);
            }
        }
        LDS_FENCE();
        bf16x8 pa = *(const bf16x8*)(myS + rdoff);
        pfrag[w] = pa;
#pragma unroll
        for (int dt = 0; dt < 4; ++dt) {
            bf16x8 vb = *(const bf16x8*)(vbase + (size_t)dt * 16 * 512 + w * 32);
            o[dt] = mfma16(pa, vb, o[dt]);
        }
    }

#pragma unroll
    for (int r = 0; r < 4; ++r) {
        psum[r] += __shfl_xor(psum[r], 1);
        psum[r] += __shfl_xor(psum[r], 2);
        psum[r] += __shfl_xor(psum[r], 4);
        psum[r] += __shfl_xor(psum[r], 8);
    }
    float inv[4];
#pragma unroll
    for (int r = 0; r < 4; ++r) inv[r] = 1.f / psum[r];

    // inv for THIS lane's row lr: held as inv[lr&3] on lanes of group lg=lr>>2
    const int srcl = (lr >> 2) << 4;
    const float v0 = __shfl(inv[0], srcl);
    const float v1 = __shfl(inv[1], srcl);
    const float v2 = __shfl(inv[2], srcl);
    const float v3 = __shfl(inv[3], srcl);
    const int sel = lr & 3;
    const float invlr = (sel == 0) ? v0 : (sel == 1) ? v1 : (sel == 2) ? v2 : v3;

    // normalized fp32 scores, direct write: row q0+lr, cols w*32 + lg*8 ..
    float* scrow = sc + ((size_t)((h * 16 + b) * 512 + q0 + lr)) * 512 + lg * 8;
#pragma unroll
    for (int w = 0; w < 16; ++w) {
        const bf16x8 pf = pfrag[w];
        float4 o0, o1;
        o0.x = (float)pf[0] * invlr; o0.y = (float)pf[1] * invlr;
        o0.z = (float)pf[2] * invlr; o0.w = (float)pf[3] * invlr;
        o1.x = (float)pf[4] * invlr; o1.y = (float)pf[5] * invlr;
        o1.z = (float)pf[6] * invlr; o1.w = (float)pf[7] * invlr;
        *(float4*)(scrow + w * 32) = o0;
        *(float4*)(scrow + w * 32 + 4) = o1;
    }

#pragma unroll
    for (int dt = 0; dt < 4; ++dt) {
#pragma unroll
        for (int r = 0; r < 4; ++r) {
            const float val = o[dt][r] * inv[r];
            const size_t gi = (size_t)(b * 512 + q0 + lg * 4 + r) * 768 + h * 64 + dt * 16 + lr;
            ctxf[gi] = val;
            ctxf[gi + (size_t)NQ] = val;
        }
    }
}

// ---------------------------------------------------------------------------
extern "C" void kernel_launch(void* const* d_in, const int* in_sizes, int n_in,
                              void* d_out, int out_size, void* d_ws, size_t ws_size,
                              hipStream_t stream)
{
    if (n_in < 11) return;
    const float* seq1 = (const float*)d_in[0];
    const float* seq2 = (const float*)d_in[1];
    const float* Wq  = (const float*)d_in[2];
    const float* Wk  = (const float*)d_in[3];
    const float* Wv  = (const float*)d_in[4];
    const float* Wq1 = (const float*)d_in[5];
    const float* bq1 = (const float*)d_in[6];
    const float* Wk1 = (const float*)d_in[7];
    const float* bk1 = (const float*)d_in[8];
    const float* Wv1 = (const float*)d_in[9];
    const float* bv1 = (const float*)d_in[10];

    if (ws_size < ((size_t)7 * NQ + 9 * NW) * 2) return;
    u16* ws   = (u16*)d_ws;
    u16* q    = ws;
    u16* kk   = ws + (size_t)NQ;
    u16* vv   = ws + (size_t)2 * NQ;
    u16* vT   = ws + (size_t)3 * NQ;
    u16* ctx  = ws + (size_t)4 * NQ;
    u16* bs1  = ws + (size_t)5 * NQ;
    u16* bs2  = ws + (size_t)6 * NQ;
    u16* bWq  = ws + (size_t)7 * NQ;
    u16* bWk  = bWq  + (size_t)NW;
    u16* bWv  = bWk  + (size_t)NW;
    u16* bWq1 = bWv  + (size_t)NW;
    u16* bWk1 = bWq1 + (size_t)2 * NW;
    u16* bWv1 = bWk1 + (size_t)2 * NW;

    float* out = (float*)d_out;

    CvtArgs ca;
    const float* srcs[8] = {seq1, seq2, Wq, Wk, Wv, Wq1, Wk1, Wv1};
    u16* dsts[8] = {bs1, bs2, bWq, bWk, bWv, bWq1, bWk1, bWv1};
    const int n4s[8] = {NQ/4, NQ/4, NW/4, NW/4, NW/4, NW/2, NW/2, NW/2};
    int acc_blk = 0;
    for (int s = 0; s < 8; ++s) {
        ca.src[s] = srcs[s]; ca.dst[s] = dsts[s]; ca.n4[s] = n4s[s];
        ca.blk_start[s] = acc_blk;
        acc_blk += (n4s[s] + 255) / 256;
    }
    cvt_multi<<<acc_blk, 256, 0, stream>>>(ca);

    dim3 pgrid(64, 6, 3);

    // layer 1 (no bias)
    proj_gemm<<<pgrid, 256, 0, stream>>>(bs1, bs2, bWq, bWk, bWv,
                                         nullptr, nullptr, nullptr, q, kk, vv);
    vtrans<<<1536, 256, 0, stream>>>(vv, vT);
    attn_stream<<<1536, 256, 0, stream>>>(q, kk, vT, ctx);

    // layer 2
    proj_gemm<<<pgrid, 256, 0, stream>>>(ctx, ctx, bWq1, bWk1, bWv1,
                                         bq1, bk1, bv1, q, kk, vv);
    vtrans<<<1536, 256, 0, stream>>>(vv, vT);
    attn_stream<<<1536, 256, 0, stream>>>(q, kk, vT, ctx);

    // layer 3: fp32 ctx x2 + direct normalized fp32 scores
    proj_gemm<<<pgrid, 256, 0, stream>>>(ctx, ctx, bWq1 + (size_t)NW, bWk1 + (size_t)NW,
                                         bWv1 + (size_t)NW,
                                         bq1 + 768, bk1 + 768, bv1 + 768, q, kk, vv);
    vtrans<<<1536, 256, 0, stream>>>(vv, vT);
    attn_final_s<<<1536, 256, 0, stream>>>(q, kk, vT, out, out + (size_t)2 * NQ);
}